// Round 1
// baseline (160.269 us; speedup 1.0000x reference)
//
#include <hip/hip_runtime.h>

// Shapes fixed by the reference: N=M=512, B=1, C=256, H=8, Dh=32, fp32.
#define LDSP 516  // padded row stride (words) for p_lds: 516%32=4 -> distinct banks per head

// ---------------- Kernel 1: transpose Wq/Wk/Wv (256x256 each) ----------------
__global__ __launch_bounds__(256) void k_transpose(const float* __restrict__ Wq,
                                                   const float* __restrict__ Wk,
                                                   const float* __restrict__ Wv,
                                                   float* __restrict__ wt) {
  const float* W = (blockIdx.y == 0) ? Wq : (blockIdx.y == 1) ? Wk : Wv;
  float* O = wt + (size_t)blockIdx.y * 65536;
  __shared__ float t[64][65];
  const int tile = blockIdx.x;
  const int tr = (tile >> 2) * 64, tc = (tile & 3) * 64;
  const int c = threadIdx.x & 63, r0 = threadIdx.x >> 6;
#pragma unroll
  for (int i = 0; i < 16; ++i) {
    int r = r0 + i * 4;
    t[r][c] = W[(tr + r) * 256 + tc + c];
  }
  __syncthreads();
#pragma unroll
  for (int i = 0; i < 16; ++i) {
    int r = r0 + i * 4;
    O[(tc + r) * 256 + tr + c] = t[c][r];  // O[a][b] = W[b][a]
  }
}

// ---------------- Kernel 2: projections q,k,v = x @ W^T + b ----------------
__global__ __launch_bounds__(256) void k_proj(const float* __restrict__ q_in,
                                              const float* __restrict__ k_in,
                                              const float* __restrict__ v_in,
                                              const float* __restrict__ bq,
                                              const float* __restrict__ bk,
                                              const float* __restrict__ bv,
                                              const float* __restrict__ wt,
                                              float* __restrict__ outb) {
  const int mat = blockIdx.y;
  const float* x = mat == 0 ? q_in : mat == 1 ? k_in : v_in;
  const float* b = mat == 0 ? bq : mat == 1 ? bk : bv;
  const float* WT = wt + (size_t)mat * 65536;
  float* out = outb + (size_t)mat * 131072;

  __shared__ float xl[8][256];
  const int tid = threadIdx.x;
  const int n0 = blockIdx.x * 8;
  for (int idx = tid; idx < 2048; idx += 256)
    xl[idx >> 8][idx & 255] = x[(n0 + (idx >> 8)) * 256 + (idx & 255)];
  __syncthreads();

  float acc[8] = {0.f, 0.f, 0.f, 0.f, 0.f, 0.f, 0.f, 0.f};
  for (int j = 0; j < 256; j += 4) {
    const float w0 = WT[(j + 0) * 256 + tid];
    const float w1 = WT[(j + 1) * 256 + tid];
    const float w2 = WT[(j + 2) * 256 + tid];
    const float w3 = WT[(j + 3) * 256 + tid];
#pragma unroll
    for (int r = 0; r < 8; ++r) {
      const float4 xv = *(const float4*)&xl[r][j];
      acc[r] += xv.x * w0 + xv.y * w1 + xv.z * w2 + xv.w * w3;
    }
  }
  const float bb = b[tid];
#pragma unroll
  for (int r = 0; r < 8; ++r) out[(n0 + r) * 256 + tid] = acc[r] + bb;
}

// ---------------- Kernel 3: fused scores_p + scores_e + softmax + attn@v ----------------
// One block per n (512 blocks, 256 threads = 4 waves).
__global__ __launch_bounds__(256) void k_main(const float* __restrict__ Eg,
                                              const float* __restrict__ Wg,
                                              const float* __restrict__ bg,
                                              const float* __restrict__ qkv,
                                              float* __restrict__ out) {
  const float* q_g = qkv;
  const float* k_g = qkv + 131072;
  const float* v_g = qkv + 262144;
  const int n = blockIdx.x;
  const int tid = threadIdx.x;
  const int lane = tid & 63, w = tid >> 6;
  const int g = lane >> 3, s = lane & 7;

  __shared__ float ql[256];
  __shared__ float tl[8 * 256];
  __shared__ float p_lds[8 * LDSP];
  __shared__ float qbl[8];
  __shared__ float invd[8];

  ql[tid] = q_g[n * 256 + tid];
  __syncthreads();

  // t[h][j] = sum_{i in head h} q[n,i] * Wg[i,j]  (thread = column j, coalesced Wg rows)
#pragma unroll
  for (int h = 0; h < 8; ++h) {
    float a = 0.f;
    const float* wg = Wg + (h * 32) * 256 + tid;
#pragma unroll
    for (int i = 0; i < 32; ++i) a = fmaf(ql[h * 32 + i], wg[(size_t)i * 256], a);
    tl[h * 256 + tid] = a;
  }
  // qb[h] = sum_{i in head h} q[n,i] * bg[i]
  {
    float pp = ql[tid] * bg[tid];
#pragma unroll
    for (int off = 1; off < 32; off <<= 1) pp += __shfl_xor(pp, off);
    if ((lane & 31) == 0) qbl[tid >> 5] = pp;
  }
  __syncthreads();

  float4 qr[8];
  float qbr[8];
#pragma unroll
  for (int j = 0; j < 8; ++j) qr[j] = *(const float4*)&ql[j * 32 + s * 4];
#pragma unroll
  for (int h = 0; h < 8; ++h) qbr[h] = qbl[h];

  const float scale = 0.17677669529663687f;  // 1/sqrt(32)

  // Main loop: wave w covers rows [w*128, (w+1)*128), 16 rows/iter (2 per lane).
  for (int it = 0; it < 8; ++it) {
    const int base = w * 128 + it * 16;
    const int m0 = base + g;
    const float* E0 = Eg + ((size_t)n * 512 + m0) * 256 + s * 4;
    const float* K0 = k_g + (size_t)m0 * 256 + s * 4;
    float acc0[8] = {0.f, 0.f, 0.f, 0.f, 0.f, 0.f, 0.f, 0.f};
    float acc1[8] = {0.f, 0.f, 0.f, 0.f, 0.f, 0.f, 0.f, 0.f};
#pragma unroll
    for (int j = 0; j < 8; ++j) {
      const int c0 = j * 32;
      const float4 ea = *(const float4*)(E0 + c0);
      const float4 eb = *(const float4*)(E0 + 2048 + c0);
      const float4 ka = *(const float4*)(K0 + c0);
      const float4 kb = *(const float4*)(K0 + 2048 + c0);
      const float4 q4 = qr[j];
      // scores_e: chunk j covers exactly head j's 32 channels
      acc0[j] += ka.x * q4.x + ka.y * q4.y + ka.z * q4.z + ka.w * q4.w;
      acc1[j] += kb.x * q4.x + kb.y * q4.y + kb.z * q4.z + kb.w * q4.w;
#pragma unroll
      for (int h = 0; h < 8; ++h) {
        const float4 t4 = *(const float4*)&tl[h * 256 + c0 + s * 4];
        acc0[h] += ea.x * t4.x + ea.y * t4.y + ea.z * t4.z + ea.w * t4.w;
        acc1[h] += eb.x * t4.x + eb.y * t4.y + eb.z * t4.z + eb.w * t4.w;
      }
    }
    // reduce over s (8 lanes), all lanes end with the total
#pragma unroll
    for (int h = 0; h < 8; ++h) {
      float a0 = acc0[h], a1 = acc1[h];
      a0 += __shfl_xor(a0, 1); a0 += __shfl_xor(a0, 2); a0 += __shfl_xor(a0, 4);
      a1 += __shfl_xor(a1, 1); a1 += __shfl_xor(a1, 2); a1 += __shfl_xor(a1, 4);
      const float s0 = (a0 + qbr[h]) * scale;
      const float s1 = (a1 + qbr[h]) * scale;
      if (s == h) {
        p_lds[h * LDSP + m0] = s0;
        p_lds[h * LDSP + m0 + 8] = s1;
      }
    }
  }
  __syncthreads();

  // Softmax over m per head; wave w handles heads 2w, 2w+1
#pragma unroll
  for (int hh = 0; hh < 2; ++hh) {
    const int h = w * 2 + hh;
    float vals[8];
#pragma unroll
    for (int i = 0; i < 8; ++i) vals[i] = p_lds[h * LDSP + lane + i * 64];
    float mx = vals[0];
#pragma unroll
    for (int i = 1; i < 8; ++i) mx = fmaxf(mx, vals[i]);
#pragma unroll
    for (int off = 1; off < 64; off <<= 1) mx = fmaxf(mx, __shfl_xor(mx, off));
    float sum = 0.f;
#pragma unroll
    for (int i = 0; i < 8; ++i) {
      const float e = __expf(vals[i] - mx);
      sum += e;
      p_lds[h * LDSP + lane + i * 64] = e;
    }
#pragma unroll
    for (int off = 1; off < 64; off <<= 1) sum += __shfl_xor(sum, off);
    if (lane == 0) invd[h] = 1.f / sum;
  }
  __syncthreads();

  float ir[8];
#pragma unroll
  for (int h = 0; h < 8; ++h) ir[h] = invd[h];

  // attn output: (B,H,N,M) at offset 131072
  float* attn_out = out + 131072;
#pragma unroll
  for (int h = 0; h < 8; ++h) {
    attn_out[(size_t)h * 262144 + n * 512 + tid] = p_lds[h * LDSP + tid] * ir[h];
    attn_out[(size_t)h * 262144 + n * 512 + 256 + tid] = p_lds[h * LDSP + 256 + tid] * ir[h];
  }

  // hidden[n, c] = (sum_m p[h][m] * v[m, c]) * invd[h],  c = tid, h = c>>5
  const int h2 = tid >> 5;
  float acc = 0.f;
  const float* vp = v_g + tid;
  const float* pr = &p_lds[h2 * LDSP];
#pragma unroll 4
  for (int m4 = 0; m4 < 128; ++m4) {
    const float4 p4 = *(const float4*)(pr + m4 * 4);
    const int mb = m4 * 4;
    acc = fmaf(p4.x, vp[(size_t)(mb + 0) * 256], acc);
    acc = fmaf(p4.y, vp[(size_t)(mb + 1) * 256], acc);
    acc = fmaf(p4.z, vp[(size_t)(mb + 2) * 256], acc);
    acc = fmaf(p4.w, vp[(size_t)(mb + 3) * 256], acc);
  }
  out[n * 256 + tid] = acc * ir[h2];
}

extern "C" void kernel_launch(void* const* d_in, const int* in_sizes, int n_in,
                              void* d_out, int out_size, void* d_ws, size_t ws_size,
                              hipStream_t stream) {
  const float* query = (const float*)d_in[0];
  const float* key   = (const float*)d_in[1];
  const float* value = (const float*)d_in[2];
  const float* Eg    = (const float*)d_in[3];
  const float* Wq    = (const float*)d_in[4];
  const float* bq    = (const float*)d_in[5];
  const float* Wk    = (const float*)d_in[6];
  const float* bk    = (const float*)d_in[7];
  const float* Wv    = (const float*)d_in[8];
  const float* bv    = (const float*)d_in[9];
  const float* Wg    = (const float*)d_in[10];
  const float* bg    = (const float*)d_in[11];
  float* out = (float*)d_out;

  // ws layout (floats): wt[3*65536] | qkv[3*131072]  -> ~2.4 MB total
  float* ws = (float*)d_ws;
  float* wt = ws;
  float* qkv = ws + 3 * 65536;

  k_transpose<<<dim3(16, 3), 256, 0, stream>>>(Wq, Wk, Wv, wt);
  k_proj<<<dim3(64, 3), 256, 0, stream>>>(query, key, value, bq, bk, bv, wt, qkv);
  k_main<<<dim3(512), 256, 0, stream>>>(Eg, Wg, bg, qkv, out);
}